// Round 2
// baseline (507.070 us; speedup 1.0000x reference)
//
#include <hip/hip_runtime.h>

// Locally-connected conv, ALL FP32 (reference dtypes).
//   x:   (32, 16, 64, 64)        float
//   w:   (60, 60, 16, 5, 5, 16)  float   (per-position 400x16 block, k innermost)
//   out: (32, 16, 60, 60)        float
// One block per output position (i,j): C[32x16] = X[32x400] * W[400x16].
// 128 threads, thread tile 2b x 2k; W staged in 4 transposed K-chunks.

#define OUT_HW 60
#define IN_HW  64
#define CIN    16
#define COUT   16
#define KS     5
#define MTOT   400            // CIN*KS*KS
#define NB     32
#define XPAD   404            // row stride: 16B-aligned (404*4%16==0), bank stride 20 -> <=2-way
#define MCHUNK 100
#define WPAD   104            // 104*4%16==0

__global__ __launch_bounds__(128)
void lc_fwd_f32(const float* __restrict__ x, const float* __restrict__ w,
                float* __restrict__ out) {
    __shared__ float sX[NB * XPAD];          // 51,712 B
    __shared__ float sWt[COUT * WPAD];       //  6,656 B  (transposed chunk: [k][m_local])

    const int j   = blockIdx.x;
    const int i   = blockIdx.y;
    const int tid = threadIdx.x;

    // ---- stage X: 12800 floats; e -> (b, c, u, v), consecutive e = consecutive v ----
    for (int e = tid; e < NB * MTOT; e += 128) {
        const int b = e / MTOT;
        const int r = e - b * MTOT;          // r = c*25 + u*5 + v
        const int c = r / (KS * KS);
        const int t = r - c * (KS * KS);
        const int u = t / KS;
        const int v = t - u * KS;
        sX[b * XPAD + r] = x[((size_t)(b * CIN + c) * IN_HW + (i + u)) * IN_HW + (j + v)];
    }

    const float* wpos = w + (size_t)(i * OUT_HW + j) * (MTOT * COUT);

    const int bp = tid & 15;                 // b = bp, bp+16
    const int kp = tid >> 4;                 // k = kp, kp+8  (kp in 0..7)
    float acc00 = 0.f, acc01 = 0.f, acc10 = 0.f, acc11 = 0.f;

    const float* xr0 = &sX[bp * XPAD];
    const float* xr1 = &sX[(bp + 16) * XPAD];
    const float* wr0 = &sWt[kp * WPAD];
    const float* wr1 = &sWt[(kp + 8) * WPAD];

    for (int mc = 0; mc < MTOT / MCHUNK; ++mc) {
        if (mc) __syncthreads();             // compute(mc-1) done before sWt overwrite
        // stage W chunk (1600 contiguous floats), transpose [m][k] -> sWt[k][m_local]
        for (int e = tid; e < MCHUNK * COUT; e += 128) {
            const int k  = e & 15;           // global index g = mc*1600+e; g%16 == e%16
            const int ml = e >> 4;           // g/16 - mc*100 == e/16
            sWt[k * WPAD + ml] = wpos[mc * (MCHUNK * COUT) + e];
        }
        __syncthreads();                     // also covers X staging when mc==0

        const int mg = mc * MCHUNK;
#pragma unroll 5
        for (int mq = 0; mq < MCHUNK; mq += 4) {
            const float4 xa = *(const float4*)&xr0[mg + mq];
            const float4 xb = *(const float4*)&xr1[mg + mq];
            const float4 wa = *(const float4*)&wr0[mq];
            const float4 wb = *(const float4*)&wr1[mq];
            acc00 = fmaf(xa.x, wa.x, acc00); acc00 = fmaf(xa.y, wa.y, acc00);
            acc00 = fmaf(xa.z, wa.z, acc00); acc00 = fmaf(xa.w, wa.w, acc00);
            acc01 = fmaf(xa.x, wb.x, acc01); acc01 = fmaf(xa.y, wb.y, acc01);
            acc01 = fmaf(xa.z, wb.z, acc01); acc01 = fmaf(xa.w, wb.w, acc01);
            acc10 = fmaf(xb.x, wa.x, acc10); acc10 = fmaf(xb.y, wa.y, acc10);
            acc10 = fmaf(xb.z, wa.z, acc10); acc10 = fmaf(xb.w, wa.w, acc10);
            acc11 = fmaf(xb.x, wb.x, acc11); acc11 = fmaf(xb.y, wb.y, acc11);
            acc11 = fmaf(xb.z, wb.z, acc11); acc11 = fmaf(xb.w, wb.w, acc11);
        }
    }

    const int oij = i * OUT_HW + j;
    const size_t HW = (size_t)OUT_HW * OUT_HW;
    out[((size_t)bp        * COUT + kp    ) * HW + oij] = acc00;
    out[((size_t)bp        * COUT + kp + 8) * HW + oij] = acc01;
    out[((size_t)(bp + 16) * COUT + kp    ) * HW + oij] = acc10;
    out[((size_t)(bp + 16) * COUT + kp + 8) * HW + oij] = acc11;
}

extern "C" void kernel_launch(void* const* d_in, const int* in_sizes, int n_in,
                              void* d_out, int out_size, void* d_ws, size_t ws_size,
                              hipStream_t stream) {
    const float* x = (const float*)d_in[0];
    const float* w = (const float*)d_in[1];
    float* out = (float*)d_out;
    dim3 grid(OUT_HW, OUT_HW);
    lc_fwd_f32<<<grid, 128, 0, stream>>>(x, w, out);
}

// Round 3
// 250.515 us; speedup vs baseline: 2.0241x; 2.0241x over previous
//
#include <hip/hip_runtime.h>

// Locally-connected conv, ALL FP32.
//   x:   (32, 16, 64, 64)        float
//   w:   (60, 60, 16, 5, 5, 16)  float   (per-position 400x16, k innermost)
//   out: (32, 16, 60, 60)        float
//
// Structure: W is the 92 MB once-read stream -> make it the coalesced axis.
// Lane (mq = lane>>4, k = lane&15) loads w[4s+mq][k] = wpos + s*256B + lane*4B
// (perfect 256B/wave) and does all 32 batch-FMAs from registers, x read as
// float4 of consecutive b from pre-transposed XT[c][h][w][b] (prepass).
// K-split across 2 waves/block; shfl+LDS reduce; packed writes + transpose
// epilogue kernel for coalesced output.

#define OUT_HW 60
#define IN_HW  64
#define CIN    16
#define COUT   16
#define KS     5
#define MTOT   400
#define NB     32
#define NPOS   3600          // OUT_HW*OUT_HW
#define BK     512           // NB*COUT
#define CHW    65536         // CIN*IN_HW*IN_HW

// ---- prepass: x[b][chw] -> xt[chw][b] (tiled transpose, coalesced both ways)
__global__ __launch_bounds__(256)
void transpose_x(const float* __restrict__ x, float* __restrict__ xt) {
    __shared__ float tile[32][65];
    const int n0 = blockIdx.x * 64;
    const int t  = threadIdx.x;
    const int tx = t & 63, ty = t >> 6;
    for (int bb = ty; bb < 32; bb += 4)
        tile[bb][tx] = x[(size_t)bb * CHW + n0 + tx];
    __syncthreads();
    const int b = t & 31;
    for (int nn = t >> 5; nn < 64; nn += 8)
        xt[(size_t)(n0 + nn) * 32 + b] = tile[b][nn];
}

// ---- main: one block (128 thr = 2 K-split waves) per output position ----
template<bool RAW>
__global__ __launch_bounds__(128)
void lc_main(const float* __restrict__ xsrc, const float* __restrict__ w,
             float* __restrict__ dst, int packed) {
    __shared__ int   sLUT[MTOT];
    __shared__ float sRed[2][NB][COUT];

    const int bid = blockIdx.x;                 // 0..3599
    const int i = bid / OUT_HW, j = bid - i * OUT_HW;
    const int t = threadIdx.x;

    for (int m = t; m < MTOT; m += 128) {
        const int c = m / (KS * KS);
        const int r = m - c * (KS * KS);
        const int u = r / KS, v = r - u * KS;
        const int n = c * (IN_HW * IN_HW) + u * IN_HW + v;
        sLUT[m] = RAW ? n : n * NB;
    }
    __syncthreads();

    const int lane = t & 63;
    const int wv   = t >> 6;                    // K-split half: 0,1
    const int mq   = lane >> 4;
    const int k    = lane & 15;

    const int posoff = RAW ? (i * IN_HW + j) : ((i * IN_HW + j) * NB);
    const float* wpos = w + (size_t)bid * (MTOT * COUT);

    float acc[NB];
#pragma unroll
    for (int b = 0; b < NB; ++b) acc[b] = 0.f;

    const int s0 = wv * 50;
#pragma unroll 2
    for (int s = s0; s < s0 + 50; ++s) {
        const int m = 4 * s + mq;
        const float wval = wpos[m * COUT + k];  // el = 64s + lane: coalesced 256B
        const float* xp = xsrc + (sLUT[m] + posoff);
        if (!RAW) {
#pragma unroll
            for (int b4 = 0; b4 < 8; ++b4) {
                const float4 xv = *(const float4*)(xp + b4 * 4);
                acc[b4 * 4 + 0] = fmaf(wval, xv.x, acc[b4 * 4 + 0]);
                acc[b4 * 4 + 1] = fmaf(wval, xv.y, acc[b4 * 4 + 1]);
                acc[b4 * 4 + 2] = fmaf(wval, xv.z, acc[b4 * 4 + 2]);
                acc[b4 * 4 + 3] = fmaf(wval, xv.w, acc[b4 * 4 + 3]);
            }
        } else {
#pragma unroll
            for (int b = 0; b < NB; ++b)
                acc[b] = fmaf(wval, xp[(size_t)b * CHW], acc[b]);
        }
    }

    // reduce over mq (lane bits 4,5); k (bits 0..3) preserved
#pragma unroll
    for (int b = 0; b < NB; ++b) {
        acc[b] += __shfl_xor(acc[b], 16, 64);
        acc[b] += __shfl_xor(acc[b], 32, 64);
    }
    // each lane owns b = mq*8 + r -> every (b,k) written exactly once per wave
#pragma unroll
    for (int r = 0; r < 8; ++r)
        sRed[wv][mq * 8 + r][k] = acc[mq * 8 + r];
    __syncthreads();

    const int base = t * 4;                     // 128 thr x 4 = 512 outs
    const float* r0 = &sRed[0][0][0];
    const float* r1 = &sRed[1][0][0];
    float4 o;
    o.x = r0[base + 0] + r1[base + 0];
    o.y = r0[base + 1] + r1[base + 1];
    o.z = r0[base + 2] + r1[base + 2];
    o.w = r0[base + 3] + r1[base + 3];
    if (packed) {
        *(float4*)(dst + (size_t)bid * BK + base) = o;  // [oij][bk], coalesced
    } else {
        dst[(size_t)(base + 0) * NPOS + bid] = o.x;     // direct scattered (fallback)
        dst[(size_t)(base + 1) * NPOS + bid] = o.y;
        dst[(size_t)(base + 2) * NPOS + bid] = o.z;
        dst[(size_t)(base + 3) * NPOS + bid] = o.w;
    }
}

// ---- epilogue: ws[oij][bk] -> out[bk][oij] (tiled transpose) ----
__global__ __launch_bounds__(256)
void transpose_out(const float* __restrict__ src, float* __restrict__ out) {
    __shared__ float tile[64][65];
    const int o0 = blockIdx.x * 64;             // oij tile
    const int k0 = blockIdx.y * 64;             // bk tile
    const int t  = threadIdx.x;
    const int tx = t & 63, ty = t >> 6;
    for (int r = ty; r < 64; r += 4) {
        const int oij = o0 + r;
        if (oij < NPOS) tile[r][tx] = src[(size_t)oij * BK + k0 + tx];
    }
    __syncthreads();
    for (int r = ty; r < 64; r += 4) {
        const int oij = o0 + tx;
        if (oij < NPOS) out[(size_t)(k0 + r) * NPOS + oij] = tile[tx][r];
    }
}

extern "C" void kernel_launch(void* const* d_in, const int* in_sizes, int n_in,
                              void* d_out, int out_size, void* d_ws, size_t ws_size,
                              hipStream_t stream) {
    const float* x = (const float*)d_in[0];
    const float* w = (const float*)d_in[1];
    float* out = (float*)d_out;
    float* xt  = (float*)d_ws;

    const size_t xtBytes = (size_t)CHW * NB * 4;            // 8.39 MB
    const size_t outBytes = (size_t)NPOS * BK * 4;          // 7.37 MB
    if (ws_size >= xtBytes + outBytes) {
        float* wsOut = xt + (size_t)CHW * NB;
        transpose_x<<<CHW / 64, 256, 0, stream>>>(x, xt);
        lc_main<false><<<NPOS, 128, 0, stream>>>(xt, w, wsOut, 1);
        transpose_out<<<dim3((NPOS + 63) / 64, BK / 64), 256, 0, stream>>>(wsOut, out);
    } else if (ws_size >= xtBytes) {
        transpose_x<<<CHW / 64, 256, 0, stream>>>(x, xt);
        lc_main<false><<<NPOS, 128, 0, stream>>>(xt, w, out, 0);
    } else {
        lc_main<true><<<NPOS, 128, 0, stream>>>(x, w, out, 0);
    }
}

// Round 4
// 172.757 us; speedup vs baseline: 2.9352x; 1.4501x over previous
//
#include <hip/hip_runtime.h>
#include <hip/hip_bf16.h>

// Locally-connected conv, ALL FP32 in/out, bf16 MFMA compute.
//   x:   (32, 16, 64, 64)        float
//   w:   (60, 60, 16, 5, 5, 16)  float   (per-position 400x16, k innermost)
//   out: (32, 16, 60, 60)        float
//
// Per position: D[b=32][k=16] = X[32x400] * W[400x16] via mfma_f32_16x16x32_bf16
// (2 M-tiles x 13 K-chunks). One block (4 waves, K-split) per position.
// W transposed to sW[k][m] and X to sX[b][m] in LDS (bf16, b128 writes);
// both operand fragments are then single ds_read_b128s.

#define OUT_HW 60
#define IN_HW  64
#define CIN    16
#define COUT   16
#define KS     5
#define MTOT   400
#define NB     32
#define NPOS   3600          // OUT_HW*OUT_HW
#define BK     512           // NB*COUT
#define CHW    65536         // CIN*IN_HW*IN_HW
#define XSTR   424           // LDS row stride (elements): 848B = 53*16 (b128-aligned)

typedef __attribute__((ext_vector_type(8))) short bf16x8;
typedef __attribute__((ext_vector_type(4))) float f32x4;

static __device__ __forceinline__ unsigned pk2(float a, float b) {
    union { __hip_bfloat162 h; unsigned u; } cv;
    cv.h = __float22bfloat162_rn(make_float2(a, b));
    return cv.u;
}

// ---- prepass: x[b][chw] -> xt[chw][b] (proven in round 3) ----
__global__ __launch_bounds__(256)
void transpose_x(const float* __restrict__ x, float* __restrict__ xt) {
    __shared__ float tile[32][65];
    const int n0 = blockIdx.x * 64;
    const int t  = threadIdx.x;
    const int tx = t & 63, ty = t >> 6;
    for (int bb = ty; bb < 32; bb += 4)
        tile[bb][tx] = x[(size_t)bb * CHW + n0 + tx];
    __syncthreads();
    const int b = t & 31;
    for (int nn = t >> 5; nn < 64; nn += 8)
        xt[(size_t)(n0 + nn) * 32 + b] = tile[b][nn];
}

template<int USEXT, int PACKED>
__global__ __launch_bounds__(256)
void lc_mfma(const float* __restrict__ xsrc, const float* __restrict__ w,
             float* __restrict__ dst) {
    __shared__ ushort sW[COUT * XSTR] __attribute__((aligned(16)));  // W^T[k][m]
    __shared__ ushort sX[NB * XSTR]  __attribute__((aligned(16)));   // X[b][m]
    __shared__ int    sLUT[MTOT]     __attribute__((aligned(16)));
    __shared__ float  sRed[4][NB * 17];

    const int bid = blockIdx.x;
    const int i = bid / OUT_HW, j = bid - i * OUT_HW;
    const int t = threadIdx.x;
    const float* wpos = w + (size_t)bid * (MTOT * COUT);

    // ---- LUT (m -> x flat offset) + zero K-pad (m 400..415) ----
    for (int m = t; m < MTOT; m += 256) {
        const int c = m / 25, r = m - c * 25, u = r / 5, v = r - u * 5;
        const int n = c * (IN_HW * IN_HW) + u * IN_HW + v;
        sLUT[m] = USEXT ? n * NB : n;
    }
    sW[(t >> 4) * XSTR + 400 + (t & 15)] = 0;                  // 16 rows x 16
    for (int e = t; e < 512; e += 256)
        sX[(e >> 4) * XSTR + 400 + (e & 15)] = 0;              // 32 rows x 16
    __syncthreads();

    // ---- stage W^T: thread (k=t&15) gathers 8 m-consecutive, one b128 write ----
    {
        const int k = t & 15;
        for (int mg = t >> 4; mg < 50; mg += 16) {
            const float* s = wpos + mg * 128 + k;
            float f[8];
#pragma unroll
            for (int jj = 0; jj < 8; ++jj) f[jj] = s[jj * 16];
            union { bf16x8 v; unsigned u[4]; } p;
#pragma unroll
            for (int jj = 0; jj < 4; ++jj) p.u[jj] = pk2(f[2 * jj], f[2 * jj + 1]);
            *(bf16x8*)&sW[k * XSTR + mg * 8] = p.v;
        }
    }
    // ---- stage X: thread (b=t&31) gathers 8 m-consecutive (wave = full 128B lines) ----
    {
        const int b = t & 31;
        const int xoff = USEXT ? ((i * IN_HW + j) * NB + b)
                               : (b * CHW + i * IN_HW + j);
        for (int mg = t >> 5; mg < 50; mg += 8) {
            const int4 L0 = *(const int4*)&sLUT[mg * 8];
            const int4 L1 = *(const int4*)&sLUT[mg * 8 + 4];
            float f[8];
            f[0] = xsrc[L0.x + xoff]; f[1] = xsrc[L0.y + xoff];
            f[2] = xsrc[L0.z + xoff]; f[3] = xsrc[L0.w + xoff];
            f[4] = xsrc[L1.x + xoff]; f[5] = xsrc[L1.y + xoff];
            f[6] = xsrc[L1.z + xoff]; f[7] = xsrc[L1.w + xoff];
            union { bf16x8 v; unsigned u[4]; } p;
#pragma unroll
            for (int jj = 0; jj < 4; ++jj) p.u[jj] = pk2(f[2 * jj], f[2 * jj + 1]);
            *(bf16x8*)&sX[b * XSTR + mg * 8] = p.v;
        }
    }
    __syncthreads();

    // ---- MFMA: wave wv does chunks {wv, wv+4, wv+8, wv+12} ----
    const int lane = t & 63, wv = t >> 6;
    const int l15 = lane & 15, q = lane >> 4;
    f32x4 acc0 = {0.f, 0.f, 0.f, 0.f}, acc1 = {0.f, 0.f, 0.f, 0.f};
    const ushort* pB  = &sW[l15 * XSTR + q * 8];
    const ushort* pA0 = &sX[l15 * XSTR + q * 8];
    const ushort* pA1 = &sX[(l15 + 16) * XSTR + q * 8];
    for (int c = wv; c < 13; c += 4) {
        const bf16x8 bF = *(const bf16x8*)(pB  + c * 32);
        const bf16x8 a0 = *(const bf16x8*)(pA0 + c * 32);
        const bf16x8 a1 = *(const bf16x8*)(pA1 + c * 32);
        acc0 = __builtin_amdgcn_mfma_f32_16x16x32_bf16(a0, bF, acc0, 0, 0, 0);
        acc1 = __builtin_amdgcn_mfma_f32_16x16x32_bf16(a1, bF, acc1, 0, 0, 0);
    }

    // ---- K-split reduce: partials to LDS (row stride 17 breaks conflicts) ----
#pragma unroll
    for (int r = 0; r < 4; ++r) {
        sRed[wv][(q * 4 + r) * 17 + l15]      = acc0[r];  // D rows: b = q*4+r
        sRed[wv][(q * 4 + r + 16) * 17 + l15] = acc1[r];  // tile 2: b + 16
    }
    __syncthreads();
#pragma unroll
    for (int h = 0; h < 2; ++h) {
        const int o = t + h * 256;                        // o = b*16 + k
        const int idx = (o >> 4) * 17 + (o & 15);
        const float sv = sRed[0][idx] + sRed[1][idx] + sRed[2][idx] + sRed[3][idx];
        if (PACKED) dst[(size_t)bid * BK + o] = sv;       // [oij][bk] coalesced
        else        dst[(size_t)o * NPOS + bid] = sv;     // scattered fallback
    }
}

// ---- epilogue: ws[oij][bk] -> out[bk][oij] (proven in round 3) ----
__global__ __launch_bounds__(256)
void transpose_out(const float* __restrict__ src, float* __restrict__ out) {
    __shared__ float tile[64][65];
    const int o0 = blockIdx.x * 64;
    const int k0 = blockIdx.y * 64;
    const int t  = threadIdx.x;
    const int tx = t & 63, ty = t >> 6;
    for (int r = ty; r < 64; r += 4) {
        const int oij = o0 + r;
        if (oij < NPOS) tile[r][tx] = src[(size_t)oij * BK + k0 + tx];
    }
    __syncthreads();
    for (int r = ty; r < 64; r += 4) {
        const int oij = o0 + tx;
        if (oij < NPOS) out[(size_t)(k0 + r) * NPOS + oij] = tile[tx][r];
    }
}

extern "C" void kernel_launch(void* const* d_in, const int* in_sizes, int n_in,
                              void* d_out, int out_size, void* d_ws, size_t ws_size,
                              hipStream_t stream) {
    const float* x = (const float*)d_in[0];
    const float* w = (const float*)d_in[1];
    float* out = (float*)d_out;
    float* xt  = (float*)d_ws;

    const size_t xtBytes  = (size_t)CHW * NB * 4;           // 8.39 MB
    const size_t outBytes = (size_t)NPOS * BK * 4;          // 7.37 MB
    if (ws_size >= xtBytes + outBytes) {
        float* wsOut = xt + (size_t)CHW * NB;
        transpose_x<<<CHW / 64, 256, 0, stream>>>(x, xt);
        lc_mfma<1, 1><<<NPOS, 256, 0, stream>>>(xt, w, wsOut);
        transpose_out<<<dim3((NPOS + 63) / 64, BK / 64), 256, 0, stream>>>(wsOut, out);
    } else if (ws_size >= xtBytes) {
        transpose_x<<<CHW / 64, 256, 0, stream>>>(x, xt);
        lc_mfma<1, 0><<<NPOS, 256, 0, stream>>>(xt, w, out);
    } else {
        lc_mfma<0, 0><<<NPOS, 256, 0, stream>>>(x, w, out);
    }
}